// Round 9
// baseline (196.055 us; speedup 1.0000x reference)
//
#include <hip/hip_runtime.h>
#include <cstddef>

// Problem constants (fixed by the benchmark)
namespace {
constexpr int cB = 32;      // batch
constexpr int cG = 2704;    // grid cells (52*52)
constexpr int cA = 3;       // anchors
constexpr int cC = 6;       // channels per box
constexpr int cD = 1024;    // feature depth
constexpr int cL = 20;      // text tokens
constexpr int cH = 512;     // hidden
constexpr int cK = 128;     // select_num (scalar input, fixed = 128)
constexpr int ROWS_OUT = cK + cL;  // 148
constexpr int FTHREADS = 512;            // front block size
constexpr int CHUNK = (cG + FTHREADS - 1) / FTHREADS;  // 6 cells per thread
}

using u16x8 = __attribute__((ext_vector_type(8))) unsigned short;
using f32x4 = __attribute__((ext_vector_type(4))) float;
using bf16x8 = __attribute__((ext_vector_type(8))) short;

static __device__ __forceinline__ unsigned short f2bf(float f) {
  unsigned u = __float_as_uint(f);
  unsigned rounding = 0x7fffu + ((u >> 16) & 1u);
  return (unsigned short)((u + rounding) >> 16);
}
static __device__ __forceinline__ unsigned packbf(float lo, float hi) {
  return (unsigned)f2bf(lo) | ((unsigned)f2bf(hi) << 16);
}

// ---------------------------------------------------------------------------
// Kernel 1 "front" (512 thr): blocks [0,32): per-batch top-K radix select
// (wave-shuffle scans) + fused box gather. Blocks [32,304): weight transposes
// to bf16, text cast to bf16, and per-batch counter reset.
// ---------------------------------------------------------------------------
__global__ __launch_bounds__(FTHREADS) void front_kernel(
    const float* __restrict__ boxes, const float* __restrict__ W_vs,
    const float* __restrict__ W_tx, const float* __restrict__ text,
    int* __restrict__ idx_out, float* __restrict__ out_boxes,
    unsigned short* __restrict__ Wt_vs, unsigned short* __restrict__ Wt_tx,
    unsigned short* __restrict__ text_bf, int* __restrict__ cnt) {
  __shared__ unsigned su[cG];
  __shared__ int hist[256];
  __shared__ int wsum[8];
  __shared__ int ssel[cK];
  __shared__ int s_rem;
  __shared__ unsigned s_prefix;
  __shared__ float tile[64][65];

  const int tid = threadIdx.x;
  const int lane = tid & 63;
  const int wv = tid >> 6;  // 0..7

  if (blockIdx.x < cB) {
    // ---------------- top-K for batch b ----------------
    const int b = blockIdx.x;
    for (int g = tid; g < cG; g += FTHREADS) {
      const float* p = boxes + ((size_t)(b * cG + g) * cA) * cC + 4;
      float s = (p[0] + p[cC] + p[2 * cC]) * (1.0f / 3.0f);
      unsigned bits = __float_as_uint(s);
      su[g] = (bits & 0x80000000u) ? ~bits : (bits | 0x80000000u);
    }
    __syncthreads();

    int remaining = cK;
    unsigned prefix = 0;
    for (int pass = 0; pass < 4; ++pass) {
      const int shift = 24 - 8 * pass;
      if (tid < 256) hist[tid] = 0;
      __syncthreads();
      for (int g = tid; g < cG; g += FTHREADS) {
        unsigned u = su[g];
        if ((pass == 0) || ((u >> (shift + 8)) == (prefix >> (shift + 8))))
          atomicAdd(&hist[(u >> shift) & 255], 1);
      }
      __syncthreads();
      if (tid < 256) {
        int h = hist[tid];
        int x = h;
#pragma unroll
        for (int d = 1; d < 64; d <<= 1) {
          int n = __shfl_up(x, d);
          if (lane >= d) x += n;
        }
        if (lane == 63) wsum[wv] = x;
        __syncthreads();
        int off = 0, T = 0;
#pragma unroll
        for (int w = 0; w < 4; ++w) {
          int s = wsum[w];
          T += s;
          if (w < wv) off += s;
        }
        const int pincl = x + off;
        const int pexcl = pincl - h;
        const int target = T - remaining;  // T >= remaining >= 1 invariant
        if (target >= pexcl && target < pincl) {
          s_prefix = prefix | ((unsigned)tid << shift);
          s_rem = remaining - (T - pincl);  // remaining - suffix(tid+1)
        }
      } else {
        __syncthreads();
      }
      __syncthreads();
      remaining = s_rem;
      prefix = s_prefix;
    }

    // ---- stream compaction into LDS (ascending g; ties lowest-g first) ----
    const int g0 = tid * CHUNK;
    const int g1 = min(g0 + CHUNK, cG);
    int cgt = 0, ceq = 0;
    for (int g = g0; g < g1; ++g) {
      unsigned u = su[g];
      cgt += (u > prefix);
      ceq += (u == prefix);
    }
    int packed = (cgt << 16) | ceq;
    int x = packed;
#pragma unroll
    for (int d = 1; d < 64; d <<= 1) {
      int n = __shfl_up(x, d);
      if (lane >= d) x += n;
    }
    if (lane == 63) wsum[wv] = x;
    __syncthreads();
    int off = 0;
#pragma unroll
    for (int w = 0; w < 8; ++w)
      if (w < wv) off += wsum[w];
    const int excl = x + off - packed;
    int gt_before = excl >> 16;
    int eq_before = excl & 0xffff;

    for (int g = g0; g < g1; ++g) {
      unsigned u = su[g];
      if (u > prefix) {
        ssel[gt_before + min(eq_before, remaining)] = g;
        ++gt_before;
      } else if (u == prefix) {
        if (eq_before < remaining) ssel[gt_before + eq_before] = g;
        ++eq_before;
      }
    }
    __syncthreads();

    // ---- write indices + fused box gather ----
    if (tid < cK) idx_out[b * cK + tid] = ssel[tid];
    for (int t2 = tid; t2 < cK * (cA * cC); t2 += FTHREADS) {
      const int k = t2 / 18;
      const int e = t2 - k * 18;
      out_boxes[(size_t)(b * cK + k) * 18 + e] =
          boxes[((size_t)(b * cG) + ssel[k]) * 18 + e];
    }
  } else {
    // ---------------- prep: counter reset + transposes + casts -----------
    const int t = blockIdx.x - cB;
    if (t == 0 && tid < cB) cnt[tid] = 0;  // reset per-batch counters
    if (t < 128) {
      // W_vs [1024,512] f32 -> Wt_vs [512][1024] bf16
      const int k0 = (t >> 3) * 64, n0 = (t & 7) * 64;
      for (int i = tid; i < 1024; i += FTHREADS) {
        const int kk = i >> 4, c4 = (i & 15) * 4;
        const float4 v =
            *(const float4*)(W_vs + (size_t)(k0 + kk) * cH + n0 + c4);
        tile[kk][c4 + 0] = v.x;
        tile[kk][c4 + 1] = v.y;
        tile[kk][c4 + 2] = v.z;
        tile[kk][c4 + 3] = v.w;
      }
      __syncthreads();
      for (int j = tid; j < 2048; j += FTHREADS) {
        const int nn = j >> 5, p = j & 31;
        unsigned v = packbf(tile[2 * p][nn], tile[2 * p + 1][nn]);
        *(unsigned*)(Wt_vs + (size_t)(n0 + nn) * cD + k0 + 2 * p) = v;
      }
    } else if (t < 192) {
      // W_tx [512,512] f32 -> Wt_tx [512][512] bf16
      const int t2 = t - 128;
      const int k0 = (t2 >> 3) * 64, n0 = (t2 & 7) * 64;
      for (int i = tid; i < 1024; i += FTHREADS) {
        const int kk = i >> 4, c4 = (i & 15) * 4;
        const float4 v =
            *(const float4*)(W_tx + (size_t)(k0 + kk) * cH + n0 + c4);
        tile[kk][c4 + 0] = v.x;
        tile[kk][c4 + 1] = v.y;
        tile[kk][c4 + 2] = v.z;
        tile[kk][c4 + 3] = v.w;
      }
      __syncthreads();
      for (int j = tid; j < 2048; j += FTHREADS) {
        const int nn = j >> 5, p = j & 31;
        unsigned v = packbf(tile[2 * p][nn], tile[2 * p + 1][nn]);
        *(unsigned*)(Wt_tx + (size_t)(n0 + nn) * cH + k0 + 2 * p) = v;
      }
    } else {
      // text [640,512] f32 -> bf16 (straight cast, coalesced)
      const int t3 = t - 192;
      const size_t base = (size_t)t3 * 4096;
      for (int i = tid; i < 1024; i += FTHREADS) {
        const float4 v = *(const float4*)(text + base + (size_t)i * 4);
        uint2 pv;
        pv.x = packbf(v.x, v.y);
        pv.y = packbf(v.z, v.w);
        *(uint2*)(text_bf + base + (size_t)i * 4) = pv;
      }
    }
  }
}

// ---------------------------------------------------------------------------
// GEMM body (256 thr, 4 waves 2x2, 4x4 frags, BK=32, single-buffer LDS,
// 2 barriers/K-step). C[m,n] = sum_k A[m,k]*Bt[n,k] + bias[n]; packed-row
// epilogue. LDS pitch 40 shorts.
// ---------------------------------------------------------------------------
template <int KD>
__device__ __forceinline__ void mfma_gemm_body(
    const unsigned short* __restrict__ A, const unsigned short* __restrict__ Bt,
    const float* __restrict__ bias, float* __restrict__ out, int bm, int bn,
    int rpb, int row_off, unsigned short (*As)[40], unsigned short (*Bs)[40]) {
  constexpr int NT = KD / 32;
  const int tid = threadIdx.x;
  const int wid = tid >> 6, lane = tid & 63;
  const int wr = wid >> 1, wc = wid & 1;
  const int lr = lane & 15, lg = lane >> 4;

  const int srow = tid >> 2;     // 0..63
  const int sc = (tid & 3) * 8;  // bf16 col: 0,8,16,24

  const unsigned short* pA0 = A + (size_t)(bm * 128 + srow) * KD + sc;
  const unsigned short* pA1 = pA0 + (size_t)64 * KD;
  const unsigned short* pB0 = Bt + (size_t)(bn * 128 + srow) * KD + sc;
  const unsigned short* pB1 = pB0 + (size_t)64 * KD;

  f32x4 acc[4][4];
#pragma unroll
  for (int i = 0; i < 4; ++i)
#pragma unroll
    for (int j = 0; j < 4; ++j) acc[i][j] = {0.f, 0.f, 0.f, 0.f};

  for (int t = 0; t < NT; ++t) {
    const u16x8 a0 = *(const u16x8*)(pA0 + t * 32);
    const u16x8 a1 = *(const u16x8*)(pA1 + t * 32);
    const u16x8 b0 = *(const u16x8*)(pB0 + t * 32);
    const u16x8 b1 = *(const u16x8*)(pB1 + t * 32);
    *(u16x8*)&As[srow][sc] = a0;
    *(u16x8*)&As[srow + 64][sc] = a1;
    *(u16x8*)&Bs[srow][sc] = b0;
    *(u16x8*)&Bs[srow + 64][sc] = b1;
    __syncthreads();

    bf16x8 af[4], bfr[4];
#pragma unroll
    for (int fr = 0; fr < 4; ++fr)
      af[fr] = *(const bf16x8*)&As[wr * 64 + fr * 16 + lr][lg * 8];
#pragma unroll
    for (int fc = 0; fc < 4; ++fc)
      bfr[fc] = *(const bf16x8*)&Bs[wc * 64 + fc * 16 + lr][lg * 8];
#pragma unroll
    for (int fr = 0; fr < 4; ++fr)
#pragma unroll
      for (int fc = 0; fc < 4; ++fc)
        acc[fr][fc] = __builtin_amdgcn_mfma_f32_16x16x32_bf16(
            af[fr], bfr[fc], acc[fr][fc], 0, 0, 0);
    __syncthreads();
  }

  float biasv[4];
#pragma unroll
  for (int fc = 0; fc < 4; ++fc)
    biasv[fc] = bias[bn * 128 + wc * 64 + fc * 16 + lr];

#pragma unroll
  for (int fr = 0; fr < 4; ++fr) {
#pragma unroll
    for (int fc = 0; fc < 4; ++fc) {
      const int col = bn * 128 + wc * 64 + fc * 16 + lr;
#pragma unroll
      for (int j = 0; j < 4; ++j) {
        const int row = bm * 128 + wr * 64 + fr * 16 + lg * 4 + j;
        const int bb = row / rpb;
        const int rr = row - bb * rpb;
        out[(size_t)bb * (ROWS_OUT * cH) + (size_t)(row_off + rr) * cH + col] =
            acc[fr][fc][j] + biasv[fc];
      }
    }
  }
}

// ---------------------------------------------------------------------------
// Kernel 2 "fused" (256 thr, 660 blocks, >=3 blocks/CU forced => all blocks
// co-resident => spin-wait is deadlock-free):
//   blocks [0,512):  gather, 4 batch-major slots (batches finish in 4 groups
//                    ~15us apart). selfeat stores are agent-scope (bypass
//                    XCD L2 -> device-visible); per-tile signal cnt[b]++.
//   blocks [512,532): text GEMM (no dependency on gather).
//   blocks [532,660): feature GEMM; block (bm,bn) spins until cnt[bm]==64,
//                    acquire-fence, then computes -> hidden under gather.
// ---------------------------------------------------------------------------
__global__ __launch_bounds__(256, 3) void fused_kernel(
    const float* __restrict__ feature, const int* __restrict__ idx,
    unsigned short* __restrict__ selfeat,
    const unsigned short* __restrict__ Wt_vs, const float* __restrict__ b_vs,
    const unsigned short* __restrict__ text_bf,
    const unsigned short* __restrict__ Wt_tx, const float* __restrict__ b_tx,
    float* __restrict__ out, int* __restrict__ cnt) {
  __shared__ __align__(16) unsigned char smem[20480 + 256];
  unsigned short(*As)[40] = (unsigned short(*)[40])smem;
  unsigned short(*Bs)[40] = (unsigned short(*)[40])(smem + 10240);

  const int blk = blockIdx.x;
  const int tid = threadIdx.x;

  if (blk < 512) {
    // ---------------- gather role ----------------
    float(*tile)[65] = (float(*)[65])smem;            // 32x65 f32 = 8.3KB
    int* sidx = (int*)(smem + 20480);                 // 64 ints
    const int lane = tid & 63;
    const int grp = tid >> 6;  // 0..3

#pragma unroll 1
    for (int s = 0; s < 4; ++s) {
      const int T = s * 512 + blk;  // batch-major tile order
      const int b = T >> 6;         // 64 tiles per batch
      const int r = T & 63;
      const int kc = r & 1;
      const int dq = r >> 1;  // 0..31

      if (tid < 64) sidx[tid] = idx[b * cK + kc * 64 + tid];
      __syncthreads();

      const int g = sidx[lane];
      const float* fptr = feature + (size_t)b * cD * cG +
                          (size_t)(dq * 32 + grp * 8) * cG + g;
      float f[8];
#pragma unroll
      for (int j = 0; j < 8; ++j) f[j] = fptr[(size_t)j * cG];
#pragma unroll
      for (int j = 0; j < 8; ++j) tile[grp * 8 + j][lane] = f[j];
      __syncthreads();

      const size_t obase = ((size_t)(b * cK + kc * 64)) * cD + dq * 32;
#pragma unroll
      for (int it = 0; it < 2; ++it) {
        const int i = tid + it * 256;
        const int kk = i >> 3;  // 0..63
        const int q = i & 7;    // 0..7
        unsigned lo = packbf(tile[4 * q + 0][kk], tile[4 * q + 1][kk]);
        unsigned hi = packbf(tile[4 * q + 2][kk], tile[4 * q + 3][kk]);
        unsigned long long pv = ((unsigned long long)hi << 32) | lo;
        // agent-scope store: write-through past the XCD L2 so consumers on
        // other XCDs see it without producer-side wbl2 fences
        __hip_atomic_store(
            (unsigned long long*)(selfeat + obase + (size_t)kk * cD + 4 * q),
            pv, __ATOMIC_RELAXED, __HIP_MEMORY_SCOPE_AGENT);
      }
      __syncthreads();  // drains vmcnt for all waves -> stores complete
      if (tid == 0)
        __hip_atomic_fetch_add(&cnt[b], 1, __ATOMIC_RELEASE,
                               __HIP_MEMORY_SCOPE_AGENT);
    }
  } else if (blk < 532) {
    // ---------------- text GEMM role ----------------
    const int t = blk - 512;  // 0..19 (5 x 4)
    mfma_gemm_body<512>(text_bf, Wt_tx, b_tx, out, t >> 2, t & 3, cL, cK, As,
                        Bs);
  } else {
    // ---------------- feature GEMM role (spin per batch) ----------------
    const int r = blk - 532;  // 0..127
    const int bm = r >> 2, bn = r & 3;
    if (tid == 0) {
      while (__hip_atomic_load(&cnt[bm], __ATOMIC_ACQUIRE,
                               __HIP_MEMORY_SCOPE_AGENT) < 64)
        __builtin_amdgcn_s_sleep(8);
    }
    __syncthreads();
    __builtin_amdgcn_fence(__ATOMIC_ACQUIRE, "agent");
    mfma_gemm_body<1024>(selfeat, Wt_vs, b_vs, out, bm, bn, 128, 0, As, Bs);
  }
}

// ---------------------------------------------------------------------------
extern "C" void kernel_launch(void* const* d_in, const int* in_sizes, int n_in,
                              void* d_out, int out_size, void* d_ws,
                              size_t ws_size, hipStream_t stream) {
  const float* boxes = (const float*)d_in[0];
  const float* feature = (const float*)d_in[1];
  const float* text = (const float*)d_in[2];
  const float* W_vs = (const float*)d_in[3];
  const float* b_vs = (const float*)d_in[4];
  const float* W_tx = (const float*)d_in[5];
  const float* b_tx = (const float*)d_in[6];

  float* out = (float*)d_out;                           // [B, 148, 512]
  float* out_boxes = out + (size_t)cB * ROWS_OUT * cH;  // [B, K, 3, 6]

  // workspace layout (bytes):
  //   idx      @ 0        (16 KB)
  //   selfeat  @ 16384    [4096,1024] bf16 (8 MB)
  //   Wt_vs    @ 8404992  [512][1024] bf16 (1 MB)
  //   Wt_tx    @ 9453568  [512][512]  bf16 (512 KB)
  //   text_bf  @ 9977856  [640][512]  bf16 (640 KB)
  //   cnt      @ 10633216 [32] int
  int* idx = (int*)d_ws;
  unsigned short* selfeat = (unsigned short*)((char*)d_ws + 16384);
  unsigned short* Wt_vs = (unsigned short*)((char*)d_ws + 8404992);
  unsigned short* Wt_tx = (unsigned short*)((char*)d_ws + 9453568);
  unsigned short* text_bf = (unsigned short*)((char*)d_ws + 9977856);
  int* cnt = (int*)((char*)d_ws + 10633216);

  // 1) top-K + box gather + weight/text prep + counter reset
  front_kernel<<<cB + 272, FTHREADS, 0, stream>>>(
      boxes, W_vs, W_tx, text, idx, out_boxes, Wt_vs, Wt_tx, text_bf, cnt);

  // 2) fused gather || text GEMM || feature GEMM (producer-consumer)
  fused_kernel<<<660, 256, 0, stream>>>(feature, idx, selfeat, Wt_vs, b_vs,
                                        text_bf, Wt_tx, b_tx, out, cnt);
}

// Round 10
// 80.749 us; speedup vs baseline: 2.4280x; 2.4280x over previous
//
#include <hip/hip_runtime.h>
#include <cstddef>

// Problem constants (fixed by the benchmark)
namespace {
constexpr int cB = 32;      // batch
constexpr int cG = 2704;    // grid cells (52*52)
constexpr int cA = 3;       // anchors
constexpr int cC = 6;       // channels per box
constexpr int cD = 1024;    // feature depth
constexpr int cL = 20;      // text tokens
constexpr int cH = 512;     // hidden
constexpr int cK = 128;     // select_num (scalar input, fixed = 128)
constexpr int ROWS_OUT = cK + cL;  // 148
constexpr int FTHREADS = 512;            // front block size
constexpr int CHUNK = (cG + FTHREADS - 1) / FTHREADS;  // 6 cells per thread
}

using u16x8 = __attribute__((ext_vector_type(8))) unsigned short;
using f32x4 = __attribute__((ext_vector_type(4))) float;
using bf16x8 = __attribute__((ext_vector_type(8))) short;

static __device__ __forceinline__ unsigned short f2bf(float f) {
  unsigned u = __float_as_uint(f);
  unsigned rounding = 0x7fffu + ((u >> 16) & 1u);
  return (unsigned short)((u + rounding) >> 16);
}
static __device__ __forceinline__ unsigned packbf(float lo, float hi) {
  return (unsigned)f2bf(lo) | ((unsigned)f2bf(hi) << 16);
}

// ---------------------------------------------------------------------------
// Kernel 1 "front" (512 thr): blocks [0,32): per-batch top-K radix select
// (wave-shuffle scans) + fused box gather. Blocks [32,304): weight transposes
// to bf16 and text cast to bf16.
// ---------------------------------------------------------------------------
__global__ __launch_bounds__(FTHREADS) void front_kernel(
    const float* __restrict__ boxes, const float* __restrict__ W_vs,
    const float* __restrict__ W_tx, const float* __restrict__ text,
    int* __restrict__ idx_out, float* __restrict__ out_boxes,
    unsigned short* __restrict__ Wt_vs, unsigned short* __restrict__ Wt_tx,
    unsigned short* __restrict__ text_bf) {
  __shared__ unsigned su[cG];
  __shared__ int hist[256];
  __shared__ int wsum[8];
  __shared__ int ssel[cK];
  __shared__ int s_rem;
  __shared__ unsigned s_prefix;
  __shared__ float tile[64][65];

  const int tid = threadIdx.x;
  const int lane = tid & 63;
  const int wv = tid >> 6;  // 0..7

  if (blockIdx.x < cB) {
    // ---------------- top-K for batch b ----------------
    const int b = blockIdx.x;
    for (int g = tid; g < cG; g += FTHREADS) {
      const float* p = boxes + ((size_t)(b * cG + g) * cA) * cC + 4;
      float s = (p[0] + p[cC] + p[2 * cC]) * (1.0f / 3.0f);
      unsigned bits = __float_as_uint(s);
      su[g] = (bits & 0x80000000u) ? ~bits : (bits | 0x80000000u);
    }
    __syncthreads();

    int remaining = cK;
    unsigned prefix = 0;
    for (int pass = 0; pass < 4; ++pass) {
      const int shift = 24 - 8 * pass;
      if (tid < 256) hist[tid] = 0;
      __syncthreads();
      for (int g = tid; g < cG; g += FTHREADS) {
        unsigned u = su[g];
        if ((pass == 0) || ((u >> (shift + 8)) == (prefix >> (shift + 8))))
          atomicAdd(&hist[(u >> shift) & 255], 1);
      }
      __syncthreads();
      if (tid < 256) {
        int h = hist[tid];
        int x = h;
#pragma unroll
        for (int d = 1; d < 64; d <<= 1) {
          int n = __shfl_up(x, d);
          if (lane >= d) x += n;
        }
        if (lane == 63) wsum[wv] = x;
        __syncthreads();
        int off = 0, T = 0;
#pragma unroll
        for (int w = 0; w < 4; ++w) {
          int s = wsum[w];
          T += s;
          if (w < wv) off += s;
        }
        const int pincl = x + off;
        const int pexcl = pincl - h;
        const int target = T - remaining;  // T >= remaining >= 1 invariant
        if (target >= pexcl && target < pincl) {
          s_prefix = prefix | ((unsigned)tid << shift);
          s_rem = remaining - (T - pincl);  // remaining - suffix(tid+1)
        }
      } else {
        __syncthreads();
      }
      __syncthreads();
      remaining = s_rem;
      prefix = s_prefix;
      // next write to s_rem is >=2 barriers after this read -> safe
    }

    // ---- stream compaction into LDS (ascending g; ties lowest-g first) ----
    const int g0 = tid * CHUNK;
    const int g1 = min(g0 + CHUNK, cG);
    int cgt = 0, ceq = 0;
    for (int g = g0; g < g1; ++g) {
      unsigned u = su[g];
      cgt += (u > prefix);
      ceq += (u == prefix);
    }
    int packed = (cgt << 16) | ceq;
    int x = packed;
#pragma unroll
    for (int d = 1; d < 64; d <<= 1) {
      int n = __shfl_up(x, d);
      if (lane >= d) x += n;
    }
    if (lane == 63) wsum[wv] = x;
    __syncthreads();
    int off = 0;
#pragma unroll
    for (int w = 0; w < 8; ++w)
      if (w < wv) off += wsum[w];
    const int excl = x + off - packed;
    int gt_before = excl >> 16;
    int eq_before = excl & 0xffff;

    for (int g = g0; g < g1; ++g) {
      unsigned u = su[g];
      if (u > prefix) {
        ssel[gt_before + min(eq_before, remaining)] = g;
        ++gt_before;
      } else if (u == prefix) {
        if (eq_before < remaining) ssel[gt_before + eq_before] = g;
        ++eq_before;
      }
    }
    __syncthreads();

    // ---- write indices + fused box gather ----
    if (tid < cK) idx_out[b * cK + tid] = ssel[tid];
    for (int t2 = tid; t2 < cK * (cA * cC); t2 += FTHREADS) {
      const int k = t2 / 18;
      const int e = t2 - k * 18;
      out_boxes[(size_t)(b * cK + k) * 18 + e] =
          boxes[((size_t)(b * cG) + ssel[k]) * 18 + e];
    }
  } else {
    // ---------------- prep: transposes + casts ----------------
    const int t = blockIdx.x - cB;
    if (t < 128) {
      // W_vs [1024,512] f32 -> Wt_vs [512][1024] bf16
      const int k0 = (t >> 3) * 64, n0 = (t & 7) * 64;
      for (int i = tid; i < 1024; i += FTHREADS) {
        const int kk = i >> 4, c4 = (i & 15) * 4;
        const float4 v =
            *(const float4*)(W_vs + (size_t)(k0 + kk) * cH + n0 + c4);
        tile[kk][c4 + 0] = v.x;
        tile[kk][c4 + 1] = v.y;
        tile[kk][c4 + 2] = v.z;
        tile[kk][c4 + 3] = v.w;
      }
      __syncthreads();
      for (int j = tid; j < 2048; j += FTHREADS) {
        const int nn = j >> 5, p = j & 31;
        unsigned v = packbf(tile[2 * p][nn], tile[2 * p + 1][nn]);
        *(unsigned*)(Wt_vs + (size_t)(n0 + nn) * cD + k0 + 2 * p) = v;
      }
    } else if (t < 192) {
      // W_tx [512,512] f32 -> Wt_tx [512][512] bf16
      const int t2 = t - 128;
      const int k0 = (t2 >> 3) * 64, n0 = (t2 & 7) * 64;
      for (int i = tid; i < 1024; i += FTHREADS) {
        const int kk = i >> 4, c4 = (i & 15) * 4;
        const float4 v =
            *(const float4*)(W_tx + (size_t)(k0 + kk) * cH + n0 + c4);
        tile[kk][c4 + 0] = v.x;
        tile[kk][c4 + 1] = v.y;
        tile[kk][c4 + 2] = v.z;
        tile[kk][c4 + 3] = v.w;
      }
      __syncthreads();
      for (int j = tid; j < 2048; j += FTHREADS) {
        const int nn = j >> 5, p = j & 31;
        unsigned v = packbf(tile[2 * p][nn], tile[2 * p + 1][nn]);
        *(unsigned*)(Wt_tx + (size_t)(n0 + nn) * cH + k0 + 2 * p) = v;
      }
    } else {
      // text [640,512] f32 -> bf16 (straight cast, coalesced)
      const int t3 = t - 192;
      const size_t base = (size_t)t3 * 4096;
      for (int i = tid; i < 1024; i += FTHREADS) {
        const float4 v = *(const float4*)(text + base + (size_t)i * 4);
        uint2 pv;
        pv.x = packbf(v.x, v.y);
        pv.y = packbf(v.z, v.w);
        *(uint2*)(text_bf + base + (size_t)i * 4) = pv;
      }
    }
  }
}

// ---------------------------------------------------------------------------
// Kernel 2: gather sel_feat [B*K, D] as BF16 from feature [B, D, G] (f32).
// 2048 blocks (64k x 32d tiles) -> 8 blocks/CU. Per lane: 8 scattered
// NON-TEMPORAL loads (one-touch data) issued back-to-back, then LDS
// transpose, packed-bf16 writes. HBM scattered-fetch wall (~158MB lines).
// ---------------------------------------------------------------------------
__global__ __launch_bounds__(256) void gather_feat_kernel(
    const float* __restrict__ feature, const int* __restrict__ idx,
    unsigned short* __restrict__ selfeat) {
  const int kc = blockIdx.x;  // 0..1
  const int dc = blockIdx.y;  // 0..31
  const int b = blockIdx.z;   // 0..31
  const int tid = threadIdx.x;
  const int lane = tid & 63;
  const int grp = tid >> 6;
  __shared__ int sidx[64];
  __shared__ float tile[32][65];
  if (tid < 64) sidx[tid] = idx[b * cK + kc * 64 + tid];
  __syncthreads();

  const int g = sidx[lane];
  const float* fptr =
      feature + (size_t)b * cD * cG + (size_t)(dc * 32 + grp * 8) * cG + g;
  float f[8];
#pragma unroll
  for (int j = 0; j < 8; ++j) f[j] = __builtin_nontemporal_load(fptr + (size_t)j * cG);
#pragma unroll
  for (int j = 0; j < 8; ++j) tile[grp * 8 + j][lane] = f[j];
  __syncthreads();

  // transpose-write: 64 k-rows x 32 d as 8B packed-bf16 per thread-iter
  const size_t obase = ((size_t)(b * cK + kc * 64)) * cD + dc * 32;
#pragma unroll
  for (int it = 0; it < 2; ++it) {
    const int i = tid + it * 256;
    const int kk = i >> 3;
    const int q = i & 7;
    uint2 pv;
    pv.x = packbf(tile[4 * q + 0][kk], tile[4 * q + 1][kk]);
    pv.y = packbf(tile[4 * q + 2][kk], tile[4 * q + 3][kk]);
    *(uint2*)(selfeat + obase + (size_t)kk * cD + 4 * q) = pv;
  }
}

// ---------------------------------------------------------------------------
// Kernel 3: merged BF16 MFMA GEMMs, 512 threads (8 waves = 2/SIMD),
// 2-deep register prefetch + double-buffered LDS (1 barrier / K-step).
// Tile 128x128, wave grid 2x4, wave tile 64x32.
// ---------------------------------------------------------------------------
template <int KD>
__device__ __forceinline__ void mfma_gemm_body(
    const unsigned short* __restrict__ A, const unsigned short* __restrict__ Bt,
    const float* __restrict__ bias, float* __restrict__ out, int bm, int bn,
    int rpb, int row_off, unsigned short (*As)[128][40],
    unsigned short (*Bs)[128][40]) {
  constexpr int NT = KD / 32;  // 32 or 16 (even)
  const int tid = threadIdx.x;
  const int wid = tid >> 6, lane = tid & 63;
  const int wr = wid >> 2, wc = wid & 3;  // 2 x 4 waves
  const int lr = lane & 15, lg = lane >> 4;

  const int srow = tid >> 2;     // 0..127
  const int sc = (tid & 3) * 8;  // bf16 col: 0,8,16,24

  const unsigned short* pA = A + (size_t)(bm * 128 + srow) * KD + sc;
  const unsigned short* pB = Bt + (size_t)(bn * 128 + srow) * KD + sc;

  f32x4 acc[4][2];
#pragma unroll
  for (int i = 0; i < 4; ++i)
#pragma unroll
    for (int j = 0; j < 2; ++j) acc[i][j] = {0.f, 0.f, 0.f, 0.f};

  u16x8 xa, xb;  // prefetch set X (even tiles)
  u16x8 ya, yb;  // prefetch set Y (odd tiles)

#define LOAD_X(kt)                      \
  xa = *(const u16x8*)(pA + (kt) * 32); \
  xb = *(const u16x8*)(pB + (kt) * 32);
#define LOAD_Y(kt)                      \
  ya = *(const u16x8*)(pA + (kt) * 32); \
  yb = *(const u16x8*)(pB + (kt) * 32);
#define STORE_X(buf)                \
  *(u16x8*)&As[buf][srow][sc] = xa; \
  *(u16x8*)&Bs[buf][srow][sc] = xb;
#define STORE_Y(buf)                \
  *(u16x8*)&As[buf][srow][sc] = ya; \
  *(u16x8*)&Bs[buf][srow][sc] = yb;
#define COMPUTE(buf)                                                        \
  {                                                                         \
    bf16x8 af[4], bfr[2];                                                   \
    _Pragma("unroll") for (int fr = 0; fr < 4; ++fr) af[fr] =               \
        *(const bf16x8*)&As[buf][wr * 64 + fr * 16 + lr][lg * 8];           \
    _Pragma("unroll") for (int fc = 0; fc < 2; ++fc) bfr[fc] =              \
        *(const bf16x8*)&Bs[buf][wc * 32 + fc * 16 + lr][lg * 8];           \
    _Pragma("unroll") for (int fr = 0; fr < 4; ++fr)                        \
        _Pragma("unroll") for (int fc = 0; fc < 2; ++fc) acc[fr][fc] =      \
            __builtin_amdgcn_mfma_f32_16x16x32_bf16(af[fr], bfr[fc],        \
                                                    acc[fr][fc], 0, 0, 0);  \
  }

  LOAD_X(0);
  LOAD_Y(1);
  STORE_X(0);
  __syncthreads();

  for (int t = 0; t < NT; t += 2) {
    if (t + 2 < NT) LOAD_X(t + 2);
    COMPUTE(0);
    STORE_Y(1);
    __syncthreads();
    if (t + 3 < NT) LOAD_Y(t + 3);
    COMPUTE(1);
    if (t + 2 < NT) STORE_X(0);
    __syncthreads();
  }
#undef LOAD_X
#undef LOAD_Y
#undef STORE_X
#undef STORE_Y
#undef COMPUTE

  // epilogue: bias + packed-row store
  float biasv[2];
#pragma unroll
  for (int fc = 0; fc < 2; ++fc)
    biasv[fc] = bias[bn * 128 + wc * 32 + fc * 16 + lr];

#pragma unroll
  for (int fr = 0; fr < 4; ++fr) {
#pragma unroll
    for (int fc = 0; fc < 2; ++fc) {
      const int col = bn * 128 + wc * 32 + fc * 16 + lr;
#pragma unroll
      for (int j = 0; j < 4; ++j) {
        const int row = bm * 128 + wr * 64 + fr * 16 + lg * 4 + j;
        const int bb = row / rpb;
        const int rr = row - bb * rpb;
        out[(size_t)bb * (ROWS_OUT * cH) + (size_t)(row_off + rr) * cH + col] =
            acc[fr][fc][j] + biasv[fc];
      }
    }
  }
}

__global__ __launch_bounds__(512) void gemms_kernel(
    const unsigned short* __restrict__ selfeat,
    const unsigned short* __restrict__ Wt_vs,
    const unsigned short* __restrict__ text_bf,
    const unsigned short* __restrict__ Wt_tx, const float* __restrict__ b_vs,
    const float* __restrict__ b_tx, float* __restrict__ out) {
  __shared__ unsigned short As[2][128][40];
  __shared__ unsigned short Bs[2][128][40];
  const int blk = blockIdx.x;
  if (blk < 128) {
    // XCD-chunked swizzle: hw blocks with blk%8==x handle bm in [4x,4x+4),
    // all bn -> A-panels served from one XCD's L2 instead of 4x from HBM.
    const int w = ((blk & 7) << 4) | (blk >> 3);
    mfma_gemm_body<1024>(selfeat, Wt_vs, b_vs, out, w >> 2, w & 3, 128, 0, As,
                         Bs);
  } else {
    // linear_text: [640,512] @ Wt_tx[512,512]^T -> rows [128,148)/batch
    const int t = blk - 128;  // 20 blocks: 5 x 4
    mfma_gemm_body<512>(text_bf, Wt_tx, b_tx, out, t >> 2, t & 3, cL, cK, As,
                        Bs);
  }
}

// ---------------------------------------------------------------------------
extern "C" void kernel_launch(void* const* d_in, const int* in_sizes, int n_in,
                              void* d_out, int out_size, void* d_ws,
                              size_t ws_size, hipStream_t stream) {
  const float* boxes = (const float*)d_in[0];
  const float* feature = (const float*)d_in[1];
  const float* text = (const float*)d_in[2];
  const float* W_vs = (const float*)d_in[3];
  const float* b_vs = (const float*)d_in[4];
  const float* W_tx = (const float*)d_in[5];
  const float* b_tx = (const float*)d_in[6];

  float* out = (float*)d_out;                           // [B, 148, 512]
  float* out_boxes = out + (size_t)cB * ROWS_OUT * cH;  // [B, K, 3, 6]

  // workspace layout (bytes):
  //   idx      @ 0        (16 KB)
  //   selfeat  @ 16384    [4096,1024] bf16 (8 MB)
  //   Wt_vs    @ 8404992  [512][1024] bf16 (1 MB)
  //   Wt_tx    @ 9453568  [512][512]  bf16 (512 KB)
  //   text_bf  @ 9977856  [640][512]  bf16 (640 KB)
  int* idx = (int*)d_ws;
  unsigned short* selfeat = (unsigned short*)((char*)d_ws + 16384);
  unsigned short* Wt_vs = (unsigned short*)((char*)d_ws + 8404992);
  unsigned short* Wt_tx = (unsigned short*)((char*)d_ws + 9453568);
  unsigned short* text_bf = (unsigned short*)((char*)d_ws + 9977856);

  // 1) top-K + box gather + weight/text prep (304 blocks, 512 thr)
  front_kernel<<<cB + 272, FTHREADS, 0, stream>>>(
      boxes, W_vs, W_tx, text, idx, out_boxes, Wt_vs, Wt_tx, text_bf);

  // 2) gather selected feature columns -> sel_feat bf16 [B*K, D]
  {
    dim3 grid(2, 32, 32);
    gather_feat_kernel<<<grid, 256, 0, stream>>>(feature, idx, selfeat);
  }

  // 3) both GEMMs in one launch (128 + 20 blocks, 512 threads)
  gemms_kernel<<<148, 512, 0, stream>>>(selfeat, Wt_vs, text_bf, Wt_tx, b_vs,
                                        b_tx, out);
}